// Round 5
// baseline (2122.967 us; speedup 1.0000x reference)
//
#include <hip/hip_runtime.h>
#include <hip/hip_bf16.h>
#include <cstdint>

// STFT magnitude as fused GEMM. Round 5: occupancy attack.
// BK=32 (64B LDS rows) halves LDS to 64 KiB -> 2 blocks/CU (4 waves/SIMD),
// same per-phase work profile as round 4 (16 MFMA, ~6 ds_read, 16KB stage/phase).
//   out[b,k,t] = sqrt( (basis_r[k,:]·frame)^2 + (basis_i[k,:]·frame)^2 )
// Block tile: 128 bins x 256 frames; wave tile: 64 bins (x2 planes) x 64 frames.
// Per K-tile (2 phases):
//   ph-R {rd Ar,B | issue ALL of tile t+1 (B,A) | bar | 16 MFMA | bar}
//   ph-I {rd Ai   |                             | bar | 16 MFMA | vmcnt(0) | bar}
// Tile t+1 loads stay in flight across 2 barriers + 2 MFMA clusters (~2 phases);
// the wait drains them after this tile's MFMA is already issued.
// LDS swizzle: 64B row = 4x16B granules; granule ^= (row&3) on write-source & read.

#define FILT   2048
#define HOP    512
#define CUT    1025
#define NBATCH 32
#define TFR    626
#define NFR    (NBATCH * TFR)      // 20032
#define LSIG   320000
#define LPAD   (LSIG + FILT)       // 322048 padded signal length

#define BK 32
#define NK (FILT / BK)             // 64 K-tiles
#define BM 128
#define BN 256
#define MT 9
#define NT 79
#define MPAD 1152
#define NWG (MT * NT)              // 711

typedef __attribute__((ext_vector_type(8))) short short8;
typedef __attribute__((ext_vector_type(4))) float f32x4;

__device__ __forceinline__ short bf16r(float f) {
  __hip_bfloat16 h = __float2bfloat16(f);
  return __builtin_bit_cast(short, h);
}

__device__ __forceinline__ short8 pack8(float4 a, float4 b) {
  short8 v;
  v[0] = bf16r(a.x); v[1] = bf16r(a.y); v[2] = bf16r(a.z); v[3] = bf16r(a.w);
  v[4] = bf16r(b.x); v[5] = bf16r(b.y); v[6] = bf16r(b.z); v[7] = bf16r(b.w);
  return v;
}

__device__ __forceinline__ void gld_lds16(const short* g, short* l) {
  __builtin_amdgcn_global_load_lds(
      (const __attribute__((address_space(1))) uint32_t*)g,
      (__attribute__((address_space(3))) uint32_t*)l, 16, 0, 0);
}

__device__ __forceinline__ void barf() {
  asm volatile("" ::: "memory");
  __builtin_amdgcn_s_barrier();
  asm volatile("" ::: "memory");
}

// -------- stage 1a: reflect-padded signal, f32 -> bf16 [32][LPAD] --------
__global__ void pad_signal(const float* __restrict__ x, short* __restrict__ XP) {
  const int b = blockIdx.y;
  const int i0 = (blockIdx.x * 256 + threadIdx.x) * 8;
  if (i0 >= LPAD) return;
  const float* xb = x + (size_t)b * LSIG;
  const int j0 = i0 - 1024;
  short8 v;
  if (j0 >= 0 && j0 + 8 <= LSIG) {
    float4 a = *(const float4*)(xb + j0);
    float4 c = *(const float4*)(xb + j0 + 4);
    v = pack8(a, c);
  } else {
    #pragma unroll
    for (int e = 0; e < 8; ++e) {
      int j = j0 + e;
      j = j < 0 ? -j : (j >= LSIG ? 2 * LSIG - 2 - j : j);
      v[e] = bf16r(xb[j]);
    }
  }
  *(short8*)&XP[(size_t)b * LPAD + i0] = v;
}

// -------- stage 1b: basis f32 -> bf16, split real/imag, zero-pad rows --------
__global__ void convert_basis(const float* __restrict__ bs, short* __restrict__ A) {
  const int row = blockIdx.x;               // 0..2*MPAD-1
  const int p = row / MPAD;
  const int k = row - p * MPAD;
  const size_t dst = (size_t)row * FILT;
  const int i = threadIdx.x * 8;
  short8 v;
  if (k < CUT) {
    const float* src = bs + (size_t)(p * CUT + k) * FILT + i;
    float4 a = *(const float4*)src;
    float4 c = *(const float4*)(src + 4);
    v = pack8(a, c);
  } else {
    v = (short8)(short)0;
  }
  *(short8*)&A[dst + i] = v;
}

// -------- stage 2: fused GEMM + magnitude --------
__global__ __launch_bounds__(512, 4)
void stft_gemm8(const short* __restrict__ Aw, const short* __restrict__ XP,
                float* __restrict__ out)
{
  __shared__ alignas(16) short sA[2][256][32];   // [buf][plane*128+row][col] 32 KiB
  __shared__ alignas(16) short sB[2][256][32];   // [buf][frame row][col]     32 KiB

  const int tid  = threadIdx.x;
  const int wave = tid >> 6;
  const int lane = tid & 63;
  const int wr = wave >> 2;          // 0..1: 64-bin half
  const int wc = wave & 3;           // 0..3: 64-frame quarter

  // bijective XCD-aware block swizzle (m204)
  int bid = blockIdx.x;
  { const int q = NWG / 8, r = NWG % 8, xc = bid & 7, o = bid >> 3;
    bid = (xc < r ? xc * (q + 1) : r * (q + 1) + (xc - r) * q) + o; }
  const int by = bid / NT, bx = bid - by * NT;
  const int m0 = by * BM, n0 = bx * BN;

  // ---- staging geometry: gld_lds 1 KB/instr = 16 rows of 64 B ----
  const int lr4  = lane >> 2;                       // row within 16-row chunk
  const int soff = ((lane & 3) ^ (lr4 & 3)) * 8;    // swizzled source granule (shorts)
  const int ap   = wave >> 2;                       // A plane this wave stages
  const int arow = (wave & 3) * 32;                 // A row base within plane
  const int brow = wave * 32;                       // B frame-row base

  const short* aPtr[2];
  const short* bPtr[2];
  #pragma unroll
  for (int c = 0; c < 2; ++c) {
    aPtr[c] = Aw + (size_t)(ap * MPAD + m0 + arow + c * 16 + lr4) * FILT + soff;
    int f = n0 + brow + c * 16 + lr4;
    if (f > NFR - 1) f = NFR - 1;
    const int bb = f / TFR, tt = f - bb * TFR;
    bPtr[c] = XP + (size_t)bb * LPAD + (size_t)tt * HOP + soff;
  }

  auto stageA = [&](int bf, int k0) {     // all 8 waves together: 256 rows
    #pragma unroll
    for (int c = 0; c < 2; ++c)
      gld_lds16(aPtr[c] + k0, &sA[bf][ap * 128 + arow + c * 16][0]);
  };
  auto stageB = [&](int bf, int k0) {
    #pragma unroll
    for (int c = 0; c < 2; ++c)
      gld_lds16(bPtr[c] + k0, &sB[bf][brow + c * 16][0]);
  };

  // ---- frag-read geometry (swizzled; row mod 4 == fr mod 4) ----
  const int fr  = lane & 15;
  const int fg  = lane >> 4;                  // 0..3
  const int col = (fg ^ (fr & 3)) * 8;        // swizzled granule (shorts)

  f32x4 acc_r[4][4], acc_i[4][4];
  #pragma unroll
  for (int m = 0; m < 4; ++m)
    #pragma unroll
    for (int n = 0; n < 4; ++n) { acc_r[m][n] = (f32x4)0.f; acc_i[m][n] = (f32x4)0.f; }

  short8 a[4], b[4];

  auto rdA = [&](int p, int bf) {
    #pragma unroll
    for (int m = 0; m < 4; ++m)
      a[m] = *(const short8*)&sA[bf][p * 128 + wr * 64 + m * 16 + fr][col];
  };
  auto rdB = [&](int bf) {
    #pragma unroll
    for (int n = 0; n < 4; ++n)
      b[n] = *(const short8*)&sB[bf][wc * 64 + n * 16 + fr][col];
  };

  auto MMr = [&]() {
    __builtin_amdgcn_s_setprio(1);
    #pragma unroll
    for (int m = 0; m < 4; ++m)
      #pragma unroll
      for (int n = 0; n < 4; ++n)
        acc_r[m][n] = __builtin_amdgcn_mfma_f32_16x16x32_bf16(a[m], b[n], acc_r[m][n], 0, 0, 0);
    __builtin_amdgcn_s_setprio(0);
  };
  auto MMi = [&]() {
    __builtin_amdgcn_s_setprio(1);
    #pragma unroll
    for (int m = 0; m < 4; ++m)
      #pragma unroll
      for (int n = 0; n < 4; ++n)
        acc_i[m][n] = __builtin_amdgcn_mfma_f32_16x16x32_bf16(a[m], b[n], acc_i[m][n], 0, 0, 0);
    __builtin_amdgcn_s_setprio(0);
  };

  // ---- prologue: tile 0 -> buf 0, full drain (once) ----
  stageB(0, 0);
  stageA(0, 0);
  asm volatile("s_waitcnt vmcnt(0)" ::: "memory");
  barf();

  #pragma unroll 2
  for (int t = 0; t < NK; ++t) {
    const int b_ = t & 1, bn = b_ ^ 1;
    const int kn = ((t + 1) & (NK - 1)) * BK;   // wraps on last iter (garbage, drained)

    // ph-R: real plane. Issue ALL of tile t+1 (stays in flight ~2 phases).
    rdA(0, b_); rdB(b_);
    stageB(bn, kn);
    stageA(bn, kn);
    barf();
    MMr();
    barf();

    // ph-I: imag plane (reuse b). Wait sits after MFMA issue.
    rdA(1, b_);
    barf();
    MMi();
    asm volatile("s_waitcnt vmcnt(0)" ::: "memory");   // tile t+1 resident
    barf();
  }

  // ---- epilogue: magnitude, guarded strided write ----
  const int cl = lane & 15;
  const int rg = (lane >> 4) * 4;
  #pragma unroll
  for (int n = 0; n < 4; ++n) {
    const int f = n0 + wc * 64 + n * 16 + cl;
    if (f >= NFR) continue;
    const int bb = f / TFR, tt = f - bb * TFR;
    float* ob = out + (size_t)bb * (CUT * TFR) + tt;
    #pragma unroll
    for (int m = 0; m < 4; ++m) {
      #pragma unroll
      for (int r = 0; r < 4; ++r) {
        const int k = m0 + wr * 64 + m * 16 + rg + r;
        if (k < CUT) {
          float re = acc_r[m][n][r];
          float im = acc_i[m][n][r];
          ob[(size_t)k * TFR] = sqrtf(re * re + im * im);
        }
      }
    }
  }
}

// -------- fallback: reg-staged 128x128 (no ws needed) --------
__global__ __launch_bounds__(256, 2)
void stft_gemm_fb(const float* __restrict__ basis, const float* __restrict__ x,
                  float* __restrict__ out)
{
  __shared__ alignas(16) short sA[2][128][64];
  __shared__ alignas(16) short sB[128][64];

  const int tid  = threadIdx.x;
  const int wave = tid >> 6;
  const int lane = tid & 63;
  const int n0 = blockIdx.x * 128;
  const int m0 = blockIdx.y * 128;

  f32x4 acc_r[4][4], acc_i[4][4];
  #pragma unroll
  for (int i = 0; i < 4; ++i)
    #pragma unroll
    for (int j = 0; j < 4; ++j) { acc_r[i][j] = (f32x4)0.f; acc_i[i][j] = (f32x4)0.f; }

  const int sr = tid >> 1;
  const int sh = (tid & 1) * 32;

  for (int k0 = 0; k0 < FILT; k0 += 64) {
    #pragma unroll
    for (int p = 0; p < 2; ++p) {
      const int k = m0 + sr;
      short8 v[4];
      if (k < CUT) {
        const float* src = basis + (size_t)(p * CUT + k) * FILT + k0 + sh;
        #pragma unroll
        for (int q = 0; q < 4; ++q) {
          float4 a = *(const float4*)(src + q * 8);
          float4 b = *(const float4*)(src + q * 8 + 4);
          v[q] = pack8(a, b);
        }
      } else {
        #pragma unroll
        for (int q = 0; q < 4; ++q) v[q] = (short8)(short)0;
      }
      #pragma unroll
      for (int q = 0; q < 4; ++q) *(short8*)&sA[p][sr][sh + q * 8] = v[q];
    }
    {
      const int f = n0 + sr;
      short8 v[4];
      if (f < NFR) {
        const int b = f / TFR, t = f - b * TFR;
        const float* xb = x + (size_t)b * LSIG;
        const int j0 = t * HOP + k0 + sh - 1024;
        if (j0 >= 0 && j0 + 32 <= LSIG) {
          #pragma unroll
          for (int q = 0; q < 4; ++q) {
            float4 a  = *(const float4*)(xb + j0 + q * 8);
            float4 b2 = *(const float4*)(xb + j0 + q * 8 + 4);
            v[q] = pack8(a, b2);
          }
        } else {
          #pragma unroll
          for (int q = 0; q < 4; ++q)
            #pragma unroll
            for (int e = 0; e < 8; ++e) {
              int j = j0 + q * 8 + e;
              j = j < 0 ? -j : (j >= LSIG ? 2 * LSIG - 2 - j : j);
              v[q][e] = bf16r(xb[j]);
            }
        }
      } else {
        #pragma unroll
        for (int q = 0; q < 4; ++q) v[q] = (short8)(short)0;
      }
      #pragma unroll
      for (int q = 0; q < 4; ++q) *(short8*)&sB[sr][sh + q * 8] = v[q];
    }
    __syncthreads();

    const int ra = lane & 15;
    #pragma unroll
    for (int kk = 0; kk < 64; kk += 32) {
      const int col = kk + (lane >> 4) * 8;
      short8 arr[4], aii[4], bfr[4];
      #pragma unroll
      for (int i = 0; i < 4; ++i) {
        const int rm = (wave >> 1) * 64 + i * 16 + ra;
        arr[i] = *(const short8*)&sA[0][rm][col];
        aii[i] = *(const short8*)&sA[1][rm][col];
        const int rn = (wave & 1) * 64 + i * 16 + ra;
        bfr[i] = *(const short8*)&sB[rn][col];
      }
      #pragma unroll
      for (int i = 0; i < 4; ++i)
        #pragma unroll
        for (int j = 0; j < 4; ++j) {
          acc_r[i][j] = __builtin_amdgcn_mfma_f32_16x16x32_bf16(arr[i], bfr[j], acc_r[i][j], 0, 0, 0);
          acc_i[i][j] = __builtin_amdgcn_mfma_f32_16x16x32_bf16(aii[i], bfr[j], acc_i[i][j], 0, 0, 0);
        }
    }
    __syncthreads();
  }

  const int wm0 = m0 + (wave >> 1) * 64;
  const int wn0 = n0 + (wave & 1) * 64;
  const int cl = lane & 15;
  const int rg = (lane >> 4) * 4;
  #pragma unroll
  for (int j = 0; j < 4; ++j) {
    const int f = wn0 + j * 16 + cl;
    if (f >= NFR) continue;
    const int b = f / TFR, t = f - b * TFR;
    float* ob = out + (size_t)b * (CUT * TFR) + t;
    #pragma unroll
    for (int i = 0; i < 4; ++i) {
      #pragma unroll
      for (int r = 0; r < 4; ++r) {
        const int k = wm0 + i * 16 + rg + r;
        if (k < CUT) {
          float re = acc_r[i][j][r], im = acc_i[i][j][r];
          ob[(size_t)k * TFR] = sqrtf(re * re + im * im);
        }
      }
    }
  }
}

extern "C" void kernel_launch(void* const* d_in, const int* in_sizes, int n_in,
                              void* d_out, int out_size, void* d_ws, size_t ws_size,
                              hipStream_t stream) {
  const float* x     = (const float*)d_in[0];
  const float* basis = (const float*)d_in[1];
  float* out = (float*)d_out;

  const size_t sbytes = (size_t)NBATCH * LPAD * sizeof(short);     // 20,611,072
  const size_t abytes = (size_t)2 * MPAD * FILT * sizeof(short);   //  9,437,184

  if (ws_size >= sbytes + abytes) {
    short* XP = (short*)d_ws;
    short* A  = (short*)((char*)d_ws + sbytes);
    pad_signal<<<dim3((LPAD + 2047) / 2048, NBATCH), 256, 0, stream>>>(x, XP);
    convert_basis<<<2 * MPAD, 256, 0, stream>>>(basis, A);
    stft_gemm8<<<NWG, 512, 0, stream>>>(A, XP, out);
  } else {
    stft_gemm_fb<<<dim3(157, 9), 256, 0, stream>>>(basis, x, out);
  }
}

// Round 6
// 231.297 us; speedup vs baseline: 9.1785x; 9.1785x over previous
//
#include <hip/hip_runtime.h>
#include <hip/hip_bf16.h>
#include <cstdint>

// STFT magnitude as fused GEMM. Round 6: minimal-sync K-loop.
// Round-4 geometry (BK=64, 128x256 block, 8 waves, 128 KiB dbuf LDS, verified
// swizzle + staging), but ONE {lgkmcnt(0); vmcnt(0); barrier} per K-tile:
//   tile body: issue ALL of tile t+1 (8 gld_lds -> buf bn) at top, then
//   interleaved frag-reads + 64 MFMA from buf b (no intra-tile hazards:
//   reads hit b only, writes hit bn only), drain at tile bottom (~2400 cyc
//   of MFMA cover for every staged load).
// Occupancy is structurally 1 block/CU (acc = 128 regs); do NOT force more
// (round 5: __launch_bounds__(512,4) -> 64 VGPR -> acc spill -> 5.8 GB scratch).

#define FILT   2048
#define HOP    512
#define CUT    1025
#define NBATCH 32
#define TFR    626
#define NFR    (NBATCH * TFR)      // 20032
#define LSIG   320000
#define LPAD   (LSIG + FILT)       // 322048 padded signal length

#define BK 64
#define NK (FILT / BK)             // 32 K-tiles
#define BM 128
#define BN 256
#define MT 9
#define NT 79
#define MPAD 1152
#define NWG (MT * NT)              // 711

typedef __attribute__((ext_vector_type(8))) short short8;
typedef __attribute__((ext_vector_type(4))) float f32x4;

__device__ __forceinline__ short bf16r(float f) {
  __hip_bfloat16 h = __float2bfloat16(f);
  return __builtin_bit_cast(short, h);
}

__device__ __forceinline__ short8 pack8(float4 a, float4 b) {
  short8 v;
  v[0] = bf16r(a.x); v[1] = bf16r(a.y); v[2] = bf16r(a.z); v[3] = bf16r(a.w);
  v[4] = bf16r(b.x); v[5] = bf16r(b.y); v[6] = bf16r(b.z); v[7] = bf16r(b.w);
  return v;
}

__device__ __forceinline__ void gld_lds16(const short* g, short* l) {
  __builtin_amdgcn_global_load_lds(
      (const __attribute__((address_space(1))) uint32_t*)g,
      (__attribute__((address_space(3))) uint32_t*)l, 16, 0, 0);
}

__device__ __forceinline__ void barf() {
  asm volatile("" ::: "memory");
  __builtin_amdgcn_s_barrier();
  asm volatile("" ::: "memory");
}

// -------- stage 1a: reflect-padded signal, f32 -> bf16 [32][LPAD] --------
__global__ void pad_signal(const float* __restrict__ x, short* __restrict__ XP) {
  const int b = blockIdx.y;
  const int i0 = (blockIdx.x * 256 + threadIdx.x) * 8;
  if (i0 >= LPAD) return;
  const float* xb = x + (size_t)b * LSIG;
  const int j0 = i0 - 1024;
  short8 v;
  if (j0 >= 0 && j0 + 8 <= LSIG) {
    float4 a = *(const float4*)(xb + j0);
    float4 c = *(const float4*)(xb + j0 + 4);
    v = pack8(a, c);
  } else {
    #pragma unroll
    for (int e = 0; e < 8; ++e) {
      int j = j0 + e;
      j = j < 0 ? -j : (j >= LSIG ? 2 * LSIG - 2 - j : j);
      v[e] = bf16r(xb[j]);
    }
  }
  *(short8*)&XP[(size_t)b * LPAD + i0] = v;
}

// -------- stage 1b: basis f32 -> bf16, split real/imag, zero-pad rows --------
__global__ void convert_basis(const float* __restrict__ bs, short* __restrict__ A) {
  const int row = blockIdx.x;               // 0..2*MPAD-1
  const int p = row / MPAD;
  const int k = row - p * MPAD;
  const size_t dst = (size_t)row * FILT;
  const int i = threadIdx.x * 8;
  short8 v;
  if (k < CUT) {
    const float* src = bs + (size_t)(p * CUT + k) * FILT + i;
    float4 a = *(const float4*)src;
    float4 c = *(const float4*)(src + 4);
    v = pack8(a, c);
  } else {
    v = (short8)(short)0;
  }
  *(short8*)&A[dst + i] = v;
}

// -------- stage 2: fused GEMM + magnitude --------
__global__ __launch_bounds__(512, 2)
void stft_gemm8(const short* __restrict__ Aw, const short* __restrict__ XP,
                float* __restrict__ out)
{
  __shared__ alignas(16) short sA[2][256][64];   // [buf][plane*128+row][col] 64 KiB
  __shared__ alignas(16) short sB[2][256][64];   // [buf][frame row][col]     64 KiB

  const int tid  = threadIdx.x;
  const int wave = tid >> 6;
  const int lane = tid & 63;
  const int wr = wave >> 2;          // 0..1: 64-bin half
  const int wc = wave & 3;           // 0..3: 64-frame quarter

  // bijective XCD-aware block swizzle (m204)
  int bid = blockIdx.x;
  { const int q = NWG / 8, r = NWG % 8, xc = bid & 7, o = bid >> 3;
    bid = (xc < r ? xc * (q + 1) : r * (q + 1) + (xc - r) * q) + o; }
  const int by = bid / NT, bx = bid - by * NT;
  const int m0 = by * BM, n0 = bx * BN;

  // ---- staging geometry (pre-swizzled global source, linear LDS dest) ----
  const int lrow = lane >> 3;                 // row within 8-row chunk
  const int soff = ((lane & 7) ^ lrow) * 8;   // swizzled source col (shorts)
  const int ch0 = wave * 2, ch1 = wave * 2 + 1;

  // A sources: ws layout [2][MPAD][FILT]
  const short* aRow0 = Aw + (size_t)(m0 + ch0 * 8 + lrow) * FILT + soff;
  const short* aRow1 = Aw + (size_t)(m0 + ch1 * 8 + lrow) * FILT + soff;
  const size_t planeOff = (size_t)MPAD * FILT;

  // B sources: padded signal, frame f -> XP[b(f)] + t(f)*HOP, row stride HOP
  const short* bPtr[2][2];
  #pragma unroll
  for (int h = 0; h < 2; ++h) {
    #pragma unroll
    for (int c = 0; c < 2; ++c) {
      int f = n0 + h * 128 + (c ? ch1 : ch0) * 8 + lrow;
      if (f > NFR - 1) f = NFR - 1;
      const int bb = f / TFR, tt = f - bb * TFR;
      bPtr[h][c] = XP + (size_t)bb * LPAD + (size_t)tt * HOP + soff;
    }
  }

  auto stageA = [&](int p, int bf, int k0) {   // plane p (0=real,1=imag), 128 rows
    gld_lds16(aRow0 + (size_t)p * planeOff + k0, &sA[bf][p * 128 + ch0 * 8][0]);
    gld_lds16(aRow1 + (size_t)p * planeOff + k0, &sA[bf][p * 128 + ch1 * 8][0]);
  };
  auto stageB = [&](int h, int bf, int k0) {   // frame half h, 128 rows
    gld_lds16(bPtr[h][0] + k0, &sB[bf][h * 128 + ch0 * 8][0]);
    gld_lds16(bPtr[h][1] + k0, &sB[bf][h * 128 + ch1 * 8][0]);
  };

  // ---- frag-read geometry (swizzled ds_read; row&7 == lane&7 for all frags) ----
  const int fr = lane & 15;
  const int l7 = lane & 7;
  const int fg = lane >> 4;                       // 0..3
  const int g0 = (fg ^ l7) * 8;                   // k-half 0 granule (shorts)
  const int g1 = ((4 + fg) ^ l7) * 8;             // k-half 1

  f32x4 acc_r[4][4], acc_i[4][4];
  #pragma unroll
  for (int m = 0; m < 4; ++m)
    #pragma unroll
    for (int n = 0; n < 4; ++n) { acc_r[m][n] = (f32x4)0.f; acc_i[m][n] = (f32x4)0.f; }

  short8 a[4], b[4];

  auto rdA = [&](int p, int kh, int bf) {
    const int g = kh ? g1 : g0;
    #pragma unroll
    for (int m = 0; m < 4; ++m)
      a[m] = *(const short8*)&sA[bf][p * 128 + wr * 64 + m * 16 + fr][g];
  };
  auto rdB = [&](int kh, int bf) {
    const int g = kh ? g1 : g0;
    #pragma unroll
    for (int n = 0; n < 4; ++n)
      b[n] = *(const short8*)&sB[bf][wc * 64 + n * 16 + fr][g];
  };

  auto MMr = [&]() {
    __builtin_amdgcn_s_setprio(1);
    #pragma unroll
    for (int m = 0; m < 4; ++m)
      #pragma unroll
      for (int n = 0; n < 4; ++n)
        acc_r[m][n] = __builtin_amdgcn_mfma_f32_16x16x32_bf16(a[m], b[n], acc_r[m][n], 0, 0, 0);
    __builtin_amdgcn_s_setprio(0);
  };
  auto MMi = [&]() {
    __builtin_amdgcn_s_setprio(1);
    #pragma unroll
    for (int m = 0; m < 4; ++m)
      #pragma unroll
      for (int n = 0; n < 4; ++n)
        acc_i[m][n] = __builtin_amdgcn_mfma_f32_16x16x32_bf16(a[m], b[n], acc_i[m][n], 0, 0, 0);
    __builtin_amdgcn_s_setprio(0);
  };

  // ---- prologue: tile 0 -> buf 0, full drain ----
  stageB(0, 0, 0);
  stageB(1, 0, 0);
  stageA(0, 0, 0);
  stageA(1, 0, 0);
  asm volatile("s_waitcnt vmcnt(0)" ::: "memory");
  barf();
  // invariant at tile top: tile t resident in buf b, no outstanding vmem,
  // all waves past barrier (t-1 reads complete -> safe to overwrite bn).

  #pragma unroll 2
  for (int t = 0; t < NK; ++t) {
    const int b_ = t & 1, bn = b_ ^ 1;
    const int k1 = ((t + 1) & (NK - 1)) * BK;   // wraps on last iter (garbage, drained)

    // issue ALL of tile t+1 into bn (in flight across the whole tile body)
    stageB(0, bn, k1);
    stageB(1, bn, k1);
    stageA(0, bn, k1);
    stageA(1, bn, k1);

    // interleaved frag-reads + 64 MFMA from buf b_ (no barriers needed:
    // reads touch b_ only, stage-writes touch bn only)
    rdA(0, 0, b_); rdB(0, b_);
    MMr();
    rdA(1, 0, b_);
    MMi();
    rdA(0, 1, b_); rdB(1, b_);
    MMr();
    rdA(1, 1, b_);
    MMi();

    // tile-boundary sync: my reads done, my t+1 loads landed, everyone agrees
    asm volatile("s_waitcnt lgkmcnt(0)" ::: "memory");
    asm volatile("s_waitcnt vmcnt(0)" ::: "memory");
    barf();
  }

  // ---- epilogue: magnitude, guarded strided write ----
  const int cl = lane & 15;
  const int rg = (lane >> 4) * 4;
  #pragma unroll
  for (int n = 0; n < 4; ++n) {
    const int f = n0 + wc * 64 + n * 16 + cl;
    if (f >= NFR) continue;
    const int bb = f / TFR, tt = f - bb * TFR;
    float* ob = out + (size_t)bb * (CUT * TFR) + tt;
    #pragma unroll
    for (int m = 0; m < 4; ++m) {
      #pragma unroll
      for (int r = 0; r < 4; ++r) {
        const int k = m0 + wr * 64 + m * 16 + rg + r;
        if (k < CUT) {
          float re = acc_r[m][n][r];
          float im = acc_i[m][n][r];
          ob[(size_t)k * TFR] = sqrtf(re * re + im * im);
        }
      }
    }
  }
}

// -------- fallback: reg-staged 128x128 (no ws needed) --------
__global__ __launch_bounds__(256, 2)
void stft_gemm_fb(const float* __restrict__ basis, const float* __restrict__ x,
                  float* __restrict__ out)
{
  __shared__ alignas(16) short sA[2][128][64];
  __shared__ alignas(16) short sB[128][64];

  const int tid  = threadIdx.x;
  const int wave = tid >> 6;
  const int lane = tid & 63;
  const int n0 = blockIdx.x * 128;
  const int m0 = blockIdx.y * 128;

  f32x4 acc_r[4][4], acc_i[4][4];
  #pragma unroll
  for (int i = 0; i < 4; ++i)
    #pragma unroll
    for (int j = 0; j < 4; ++j) { acc_r[i][j] = (f32x4)0.f; acc_i[i][j] = (f32x4)0.f; }

  const int sr = tid >> 1;
  const int sh = (tid & 1) * 32;

  for (int k0 = 0; k0 < FILT; k0 += 64) {
    #pragma unroll
    for (int p = 0; p < 2; ++p) {
      const int k = m0 + sr;
      short8 v[4];
      if (k < CUT) {
        const float* src = basis + (size_t)(p * CUT + k) * FILT + k0 + sh;
        #pragma unroll
        for (int q = 0; q < 4; ++q) {
          float4 a = *(const float4*)(src + q * 8);
          float4 b = *(const float4*)(src + q * 8 + 4);
          v[q] = pack8(a, b);
        }
      } else {
        #pragma unroll
        for (int q = 0; q < 4; ++q) v[q] = (short8)(short)0;
      }
      #pragma unroll
      for (int q = 0; q < 4; ++q) *(short8*)&sA[p][sr][sh + q * 8] = v[q];
    }
    {
      const int f = n0 + sr;
      short8 v[4];
      if (f < NFR) {
        const int b = f / TFR, t = f - b * TFR;
        const float* xb = x + (size_t)b * LSIG;
        const int j0 = t * HOP + k0 + sh - 1024;
        if (j0 >= 0 && j0 + 32 <= LSIG) {
          #pragma unroll
          for (int q = 0; q < 4; ++q) {
            float4 a  = *(const float4*)(xb + j0 + q * 8);
            float4 b2 = *(const float4*)(xb + j0 + q * 8 + 4);
            v[q] = pack8(a, b2);
          }
        } else {
          #pragma unroll
          for (int q = 0; q < 4; ++q)
            #pragma unroll
            for (int e = 0; e < 8; ++e) {
              int j = j0 + q * 8 + e;
              j = j < 0 ? -j : (j >= LSIG ? 2 * LSIG - 2 - j : j);
              v[q][e] = bf16r(xb[j]);
            }
        }
      } else {
        #pragma unroll
        for (int q = 0; q < 4; ++q) v[q] = (short8)(short)0;
      }
      #pragma unroll
      for (int q = 0; q < 4; ++q) *(short8*)&sB[sr][sh + q * 8] = v[q];
    }
    __syncthreads();

    const int ra = lane & 15;
    #pragma unroll
    for (int kk = 0; kk < 64; kk += 32) {
      const int col = kk + (lane >> 4) * 8;
      short8 arr[4], aii[4], bfr[4];
      #pragma unroll
      for (int i = 0; i < 4; ++i) {
        const int rm = (wave >> 1) * 64 + i * 16 + ra;
        arr[i] = *(const short8*)&sA[0][rm][col];
        aii[i] = *(const short8*)&sA[1][rm][col];
        const int rn = (wave & 1) * 64 + i * 16 + ra;
        bfr[i] = *(const short8*)&sB[rn][col];
      }
      #pragma unroll
      for (int i = 0; i < 4; ++i)
        #pragma unroll
        for (int j = 0; j < 4; ++j) {
          acc_r[i][j] = __builtin_amdgcn_mfma_f32_16x16x32_bf16(arr[i], bfr[j], acc_r[i][j], 0, 0, 0);
          acc_i[i][j] = __builtin_amdgcn_mfma_f32_16x16x32_bf16(aii[i], bfr[j], acc_i[i][j], 0, 0, 0);
        }
    }
    __syncthreads();
  }

  const int wm0 = m0 + (wave >> 1) * 64;
  const int wn0 = n0 + (wave & 1) * 64;
  const int cl = lane & 15;
  const int rg = (lane >> 4) * 4;
  #pragma unroll
  for (int j = 0; j < 4; ++j) {
    const int f = wn0 + j * 16 + cl;
    if (f >= NFR) continue;
    const int b = f / TFR, t = f - b * TFR;
    float* ob = out + (size_t)b * (CUT * TFR) + t;
    #pragma unroll
    for (int i = 0; i < 4; ++i) {
      #pragma unroll
      for (int r = 0; r < 4; ++r) {
        const int k = wm0 + i * 16 + rg + r;
        if (k < CUT) {
          float re = acc_r[i][j][r], im = acc_i[i][j][r];
          ob[(size_t)k * TFR] = sqrtf(re * re + im * im);
        }
      }
    }
  }
}

extern "C" void kernel_launch(void* const* d_in, const int* in_sizes, int n_in,
                              void* d_out, int out_size, void* d_ws, size_t ws_size,
                              hipStream_t stream) {
  const float* x     = (const float*)d_in[0];
  const float* basis = (const float*)d_in[1];
  float* out = (float*)d_out;

  const size_t sbytes = (size_t)NBATCH * LPAD * sizeof(short);     // 20,611,072
  const size_t abytes = (size_t)2 * MPAD * FILT * sizeof(short);   //  9,437,184

  if (ws_size >= sbytes + abytes) {
    short* XP = (short*)d_ws;
    short* A  = (short*)((char*)d_ws + sbytes);
    pad_signal<<<dim3((LPAD + 2047) / 2048, NBATCH), 256, 0, stream>>>(x, XP);
    convert_basis<<<2 * MPAD, 256, 0, stream>>>(basis, A);
    stft_gemm8<<<NWG, 512, 0, stream>>>(A, XP, out);
  } else {
    stft_gemm_fb<<<dim3(157, 9), 256, 0, stream>>>(basis, x, out);
  }
}

// Round 7
// 155.828 us; speedup vs baseline: 13.6238x; 1.4843x over previous
//
#include <hip/hip_runtime.h>
#include <hip/hip_bf16.h>
#include <cstdint>

// STFT magnitude via real-packed radix-4 FFT (round 7).
// |X[k]| of hann-windowed 2048-sample frames == the reference basis GEMM,
// but 2.3 GFLOP instead of 190 GFLOP -> memory/LDS-bound.
//   z[n] = xw[2n] + i*xw[2n+1]  (n=0..1023) -> 1024-pt radix-4 DIT FFT ->
//   X[k] = Xe + W_2048^k * Xo,  Xe=(Z[k]+conj(Z[-k]))/2, Xo=-i(Z[k]-conj(Z[-k]))/2
// One wave per frame, in-place in padded LDS (P(i)=i+(i>>4)), 4 frames/wave,
// 16 frames/block. Twiddle + hann tables precomputed in ws, cached in LDS.
// Input from bf16 padded signal (proven pad_signal); error ~0.15 << 2.72 thr.

#define FILT   2048
#define HOP    512
#define CUT    1025
#define NBATCH 32
#define TFR    626
#define NFR    (NBATCH * TFR)      // 20032
#define LSIG   320000
#define LPAD   (LSIG + FILT)       // 322048
#define N2     1024                // complex FFT length

typedef __attribute__((ext_vector_type(8))) short short8;

__device__ __forceinline__ short bf16r(float f) {
  __hip_bfloat16 h = __float2bfloat16(f);
  return __builtin_bit_cast(short, h);
}

__device__ __forceinline__ short8 pack8(float4 a, float4 b) {
  short8 v;
  v[0] = bf16r(a.x); v[1] = bf16r(a.y); v[2] = bf16r(a.z); v[3] = bf16r(a.w);
  v[4] = bf16r(b.x); v[5] = bf16r(b.y); v[6] = bf16r(b.z); v[7] = bf16r(b.w);
  return v;
}

// -------- stage 1a: reflect-padded signal, f32 -> bf16 [32][LPAD] --------
__global__ void pad_signal(const float* __restrict__ x, short* __restrict__ XP) {
  const int b = blockIdx.y;
  const int i0 = (blockIdx.x * 256 + threadIdx.x) * 8;
  if (i0 >= LPAD) return;
  const float* xb = x + (size_t)b * LSIG;
  const int j0 = i0 - 1024;
  short8 v;
  if (j0 >= 0 && j0 + 8 <= LSIG) {
    float4 a = *(const float4*)(xb + j0);
    float4 c = *(const float4*)(xb + j0 + 4);
    v = pack8(a, c);
  } else {
    #pragma unroll
    for (int e = 0; e < 8; ++e) {
      int j = j0 + e;
      j = j < 0 ? -j : (j >= LSIG ? 2 * LSIG - 2 - j : j);
      v[e] = bf16r(xb[j]);
    }
  }
  *(short8*)&XP[(size_t)b * LPAD + i0] = v;
}

// -------- stage 1b: twiddle + hann tables --------
__global__ void make_tables(float* __restrict__ hann, float2* __restrict__ Tst,
                            float2* __restrict__ Tun) {
  const int i = blockIdx.x * 256 + threadIdx.x;    // 0..2047
  const float PI2 = 6.283185307179586f;
  if (i < 2048) hann[i] = 0.5f - 0.5f * cosf(PI2 * (float)i / 2048.0f);
  if (i < 1024) {
    float s, c;
    sincosf(-PI2 * (float)i / 1024.0f, &s, &c);
    Tst[i] = make_float2(c, s);                    // W_1024^i (forward)
    sincosf(-PI2 * (float)i / 2048.0f, &s, &c);
    Tun[i] = make_float2(c, s);                    // W_2048^i (unpack)
  }
}

__device__ __forceinline__ float2 cmul(float2 a, float2 b) {
  return make_float2(a.x * b.x - a.y * b.y, a.x * b.y + a.y * b.x);
}

// radix-4 DIT stage: M4 = 1<<LOG sub-size quarter, twiddle stride = 1<<(8-LOG)
template<int LOG>
__device__ __forceinline__ void fft_stage(float2* z, const float2* tw, int lane) {
  constexpr int M4 = 1 << LOG;
  constexpr int STRIDE = 1 << (8 - LOG);
  #pragma unroll
  for (int u = 0; u < 4; ++u) {
    const int bf = u * 64 + lane;                  // butterfly id 0..255
    const int j  = bf & (M4 - 1);
    const int i0 = ((bf >> LOG) << (LOG + 2)) | j;
    const int i1 = i0 + M4, i2 = i0 + 2 * M4, i3 = i0 + 3 * M4;
    const int p0 = i0 + (i0 >> 4), p1 = i1 + (i1 >> 4);
    const int p2 = i2 + (i2 >> 4), p3 = i3 + (i3 >> 4);
    float2 a = z[p0], b = z[p1], c = z[p2], d = z[p3];
    if (LOG > 0) {
      b = cmul(b, tw[j * STRIDE]);
      c = cmul(c, tw[2 * j * STRIDE]);
      d = cmul(d, tw[3 * j * STRIDE]);
    }
    const float2 t0 = make_float2(a.x + c.x, a.y + c.y);
    const float2 t1 = make_float2(a.x - c.x, a.y - c.y);
    const float2 t2 = make_float2(b.x + d.x, b.y + d.y);
    const float2 t3 = make_float2(b.x - d.x, b.y - d.y);
    z[p0] = make_float2(t0.x + t2.x, t0.y + t2.y);
    z[p1] = make_float2(t1.x + t3.y, t1.y - t3.x);   // t1 - i*t3
    z[p2] = make_float2(t0.x - t2.x, t0.y - t2.y);
    z[p3] = make_float2(t1.x - t3.y, t1.y + t3.x);   // t1 + i*t3
  }
}

// -------- stage 2: windowed rFFT magnitude, 1 wave = 1 frame --------
__global__ __launch_bounds__(256)
void stft_fft(const short* __restrict__ XP, const float* __restrict__ hann,
              const float2* __restrict__ Tst, const float2* __restrict__ Tun,
              float* __restrict__ out)
{
  __shared__ float2 zsh[4][1088];    // per-wave padded z (1024 + 64 pad)
  __shared__ float2 tst[1024];
  __shared__ float2 tun[1024];

  const int tid = threadIdx.x, wv = tid >> 6, lane = tid & 63;
  #pragma unroll
  for (int u = 0; u < 4; ++u) {
    tst[u * 256 + tid] = Tst[u * 256 + tid];
    tun[u * 256 + tid] = Tun[u * 256 + tid];
  }
  __syncthreads();

  float2* z = zsh[wv];

  for (int q = 0; q < 4; ++q) {
    const int f = blockIdx.x * 16 + wv * 4 + q;    // grid covers NFR exactly
    const int b = f / TFR, t = f - b * TFR;
    const short* base = XP + (size_t)b * LPAD + (size_t)t * HOP;

    // load pair (x[2i], x[2i+1]), window, store digit-reversed
    #pragma unroll
    for (int u = 0; u < 16; ++u) {
      const int i = u * 64 + lane;
      const uint32_t pr = *(const uint32_t*)(base + 2 * i);
      const float xe = __builtin_bit_cast(float, pr << 16);
      const float xo = __builtin_bit_cast(float, pr & 0xffff0000u);
      const float2 h = *(const float2*)(hann + 2 * i);
      int r = __brev((unsigned)i) >> 22;               // 10-bit bit-reverse
      r = ((r & 0x155) << 1) | ((r >> 1) & 0x155);     // -> base-4 digit-reverse
      z[r + (r >> 4)] = make_float2(xe * h.x, xo * h.y);
    }
    __syncthreads();

    fft_stage<0>(z, tst, lane); __syncthreads();
    fft_stage<2>(z, tst, lane); __syncthreads();
    fft_stage<4>(z, tst, lane); __syncthreads();
    fft_stage<6>(z, tst, lane); __syncthreads();
    fft_stage<8>(z, tst, lane); __syncthreads();

    // unpack real FFT + magnitude
    float* ob = out + (size_t)b * (CUT * TFR) + t;
    #pragma unroll
    for (int v = 0; v < 16; ++v) {
      const int k = v * 64 + lane;
      const float2 Zk = z[k + (k >> 4)];
      const int km = (N2 - k) & (N2 - 1);
      const float2 Zm = z[km + (km >> 4)];
      const float xer = 0.5f * (Zk.x + Zm.x);
      const float xei = 0.5f * (Zk.y - Zm.y);
      const float xor_ = 0.5f * (Zk.y + Zm.y);
      const float xoi = -0.5f * (Zk.x - Zm.x);
      const float2 w = tun[k];
      const float Xr = xer + w.x * xor_ - w.y * xoi;
      const float Xi = xei + w.x * xoi + w.y * xor_;
      ob[(size_t)k * TFR] = sqrtf(Xr * Xr + Xi * Xi);
    }
    if (lane == 0) {                                   // Nyquist bin
      const float2 Z0 = z[0];
      ob[(size_t)N2 * TFR] = fabsf(Z0.x - Z0.y);
    }
    __syncthreads();
  }
}

// -------- fallback: reg-staged 128x128 MFMA GEMM (no ws needed) --------
typedef __attribute__((ext_vector_type(4))) float f32x4;

__global__ __launch_bounds__(256, 2)
void stft_gemm_fb(const float* __restrict__ basis, const float* __restrict__ x,
                  float* __restrict__ out)
{
  __shared__ alignas(16) short sA[2][128][64];
  __shared__ alignas(16) short sB[128][64];

  const int tid  = threadIdx.x;
  const int wave = tid >> 6;
  const int lane = tid & 63;
  const int n0 = blockIdx.x * 128;
  const int m0 = blockIdx.y * 128;

  f32x4 acc_r[4][4], acc_i[4][4];
  #pragma unroll
  for (int i = 0; i < 4; ++i)
    #pragma unroll
    for (int j = 0; j < 4; ++j) { acc_r[i][j] = (f32x4)0.f; acc_i[i][j] = (f32x4)0.f; }

  const int sr = tid >> 1;
  const int sh = (tid & 1) * 32;

  for (int k0 = 0; k0 < FILT; k0 += 64) {
    #pragma unroll
    for (int p = 0; p < 2; ++p) {
      const int k = m0 + sr;
      short8 v[4];
      if (k < CUT) {
        const float* src = basis + (size_t)(p * CUT + k) * FILT + k0 + sh;
        #pragma unroll
        for (int qq = 0; qq < 4; ++qq) {
          float4 a = *(const float4*)(src + qq * 8);
          float4 b = *(const float4*)(src + qq * 8 + 4);
          v[qq] = pack8(a, b);
        }
      } else {
        #pragma unroll
        for (int qq = 0; qq < 4; ++qq) v[qq] = (short8)(short)0;
      }
      #pragma unroll
      for (int qq = 0; qq < 4; ++qq) *(short8*)&sA[p][sr][sh + qq * 8] = v[qq];
    }
    {
      const int f = n0 + sr;
      short8 v[4];
      if (f < NFR) {
        const int b = f / TFR, t = f - b * TFR;
        const float* xb = x + (size_t)b * LSIG;
        const int j0 = t * HOP + k0 + sh - 1024;
        if (j0 >= 0 && j0 + 32 <= LSIG) {
          #pragma unroll
          for (int qq = 0; qq < 4; ++qq) {
            float4 a  = *(const float4*)(xb + j0 + qq * 8);
            float4 b2 = *(const float4*)(xb + j0 + qq * 8 + 4);
            v[qq] = pack8(a, b2);
          }
        } else {
          #pragma unroll
          for (int qq = 0; qq < 4; ++qq)
            #pragma unroll
            for (int e = 0; e < 8; ++e) {
              int j = j0 + qq * 8 + e;
              j = j < 0 ? -j : (j >= LSIG ? 2 * LSIG - 2 - j : j);
              v[qq][e] = bf16r(xb[j]);
            }
        }
      } else {
        #pragma unroll
        for (int qq = 0; qq < 4; ++qq) v[qq] = (short8)(short)0;
      }
      #pragma unroll
      for (int qq = 0; qq < 4; ++qq) *(short8*)&sB[sr][sh + qq * 8] = v[qq];
    }
    __syncthreads();

    const int ra = lane & 15;
    #pragma unroll
    for (int kk = 0; kk < 64; kk += 32) {
      const int col = kk + (lane >> 4) * 8;
      short8 arr[4], aii[4], bfr[4];
      #pragma unroll
      for (int i = 0; i < 4; ++i) {
        const int rm = (wave >> 1) * 64 + i * 16 + ra;
        arr[i] = *(const short8*)&sA[0][rm][col];
        aii[i] = *(const short8*)&sA[1][rm][col];
        const int rn = (wave & 1) * 64 + i * 16 + ra;
        bfr[i] = *(const short8*)&sB[rn][col];
      }
      #pragma unroll
      for (int i = 0; i < 4; ++i)
        #pragma unroll
        for (int j = 0; j < 4; ++j) {
          acc_r[i][j] = __builtin_amdgcn_mfma_f32_16x16x32_bf16(arr[i], bfr[j], acc_r[i][j], 0, 0, 0);
          acc_i[i][j] = __builtin_amdgcn_mfma_f32_16x16x32_bf16(aii[i], bfr[j], acc_i[i][j], 0, 0, 0);
        }
    }
    __syncthreads();
  }

  const int wm0 = m0 + (wave >> 1) * 64;
  const int wn0 = n0 + (wave & 1) * 64;
  const int cl = lane & 15;
  const int rg = (lane >> 4) * 4;
  #pragma unroll
  for (int j = 0; j < 4; ++j) {
    const int f = wn0 + j * 16 + cl;
    if (f >= NFR) continue;
    const int b = f / TFR, t = f - b * TFR;
    float* ob = out + (size_t)b * (CUT * TFR) + t;
    #pragma unroll
    for (int i = 0; i < 4; ++i) {
      #pragma unroll
      for (int r = 0; r < 4; ++r) {
        const int k = wm0 + i * 16 + rg + r;
        if (k < CUT) {
          float re = acc_r[i][j][r], im = acc_i[i][j][r];
          ob[(size_t)k * TFR] = sqrtf(re * re + im * im);
        }
      }
    }
  }
}

extern "C" void kernel_launch(void* const* d_in, const int* in_sizes, int n_in,
                              void* d_out, int out_size, void* d_ws, size_t ws_size,
                              hipStream_t stream) {
  const float* x     = (const float*)d_in[0];
  const float* basis = (const float*)d_in[1];
  float* out = (float*)d_out;

  const size_t sbytes = (size_t)NBATCH * LPAD * sizeof(short);   // 20,611,072
  const size_t hbytes = 2048 * sizeof(float);                    // 8 KB
  const size_t tbytes = 1024 * sizeof(float2);                   // 8 KB each

  if (ws_size >= sbytes + hbytes + 2 * tbytes) {
    short*  XP   = (short*)d_ws;
    float*  hann = (float*)((char*)d_ws + sbytes);
    float2* Tst  = (float2*)((char*)d_ws + sbytes + hbytes);
    float2* Tun  = (float2*)((char*)d_ws + sbytes + hbytes + tbytes);
    pad_signal<<<dim3((LPAD + 2047) / 2048, NBATCH), 256, 0, stream>>>(x, XP);
    make_tables<<<8, 256, 0, stream>>>(hann, Tst, Tun);
    stft_fft<<<NFR / 16, 256, 0, stream>>>(XP, hann, Tst, Tun, out);
  } else {
    stft_gemm_fb<<<dim3(157, 9), 256, 0, stream>>>(basis, x, out);
  }
}

// Round 8
// 112.885 us; speedup vs baseline: 18.8065x; 1.3804x over previous
//
#include <hip/hip_runtime.h>
#include <hip/hip_bf16.h>
#include <cstdint>

// STFT magnitude via real-packed radix-4 FFT (round 8).
// vs round 7: (a) XOR-swizzled z layout s(i)=i^((i>>4)&15) -- verified 4-way
// (= wave64 b64 minimum) bank uniformity for all 5 stage strides -> kills the
// 1.7e7 bank conflicts; (b) no barriers inside the FFT (z is per-wave; in-wave
// LDS RAW ordering is lgkmcnt, compiler-inserted); (c) frame remap f=bid*16+
// q*4+wv + LDS mag staging so the output write is 16B-contiguous per bin
// (2x float2) instead of 4B scattered -> ~5x less HBM write traffic.

#define FILT   2048
#define HOP    512
#define CUT    1025
#define NBATCH 32
#define TFR    626
#define NFR    (NBATCH * TFR)      // 20032
#define LSIG   320000
#define LPAD   (LSIG + FILT)       // 322048
#define N2     1024                // complex FFT length

typedef __attribute__((ext_vector_type(8))) short short8;

__device__ __forceinline__ short bf16r(float f) {
  __hip_bfloat16 h = __float2bfloat16(f);
  return __builtin_bit_cast(short, h);
}

__device__ __forceinline__ short8 pack8(float4 a, float4 b) {
  short8 v;
  v[0] = bf16r(a.x); v[1] = bf16r(a.y); v[2] = bf16r(a.z); v[3] = bf16r(a.w);
  v[4] = bf16r(b.x); v[5] = bf16r(b.y); v[6] = bf16r(b.z); v[7] = bf16r(b.w);
  return v;
}

// -------- stage 1a: reflect-padded signal, f32 -> bf16 [32][LPAD] --------
__global__ void pad_signal(const float* __restrict__ x, short* __restrict__ XP) {
  const int b = blockIdx.y;
  const int i0 = (blockIdx.x * 256 + threadIdx.x) * 8;
  if (i0 >= LPAD) return;
  const float* xb = x + (size_t)b * LSIG;
  const int j0 = i0 - 1024;
  short8 v;
  if (j0 >= 0 && j0 + 8 <= LSIG) {
    float4 a = *(const float4*)(xb + j0);
    float4 c = *(const float4*)(xb + j0 + 4);
    v = pack8(a, c);
  } else {
    #pragma unroll
    for (int e = 0; e < 8; ++e) {
      int j = j0 + e;
      j = j < 0 ? -j : (j >= LSIG ? 2 * LSIG - 2 - j : j);
      v[e] = bf16r(xb[j]);
    }
  }
  *(short8*)&XP[(size_t)b * LPAD + i0] = v;
}

// -------- stage 1b: twiddle + hann tables --------
__global__ void make_tables(float* __restrict__ hann, float2* __restrict__ Tst,
                            float2* __restrict__ Tun) {
  const int i = blockIdx.x * 256 + threadIdx.x;    // 0..2047
  const float PI2 = 6.283185307179586f;
  if (i < 2048) hann[i] = 0.5f - 0.5f * cosf(PI2 * (float)i / 2048.0f);
  if (i < 1024) {
    float s, c;
    sincosf(-PI2 * (float)i / 1024.0f, &s, &c);
    Tst[i] = make_float2(c, s);                    // W_1024^i (forward)
    sincosf(-PI2 * (float)i / 2048.0f, &s, &c);
    Tun[i] = make_float2(c, s);                    // W_2048^i (unpack)
  }
}

__device__ __forceinline__ float2 cmul(float2 a, float2 b) {
  return make_float2(a.x * b.x - a.y * b.y, a.x * b.y + a.y * b.x);
}

__device__ __forceinline__ int SW(int i) { return i ^ ((i >> 4) & 15); }

// radix-4 DIT stage: M4 = 1<<LOG sub-size quarter, twiddle stride = 1<<(8-LOG)
template<int LOG>
__device__ __forceinline__ void fft_stage(float2* z, const float2* tw, int lane) {
  constexpr int M4 = 1 << LOG;
  constexpr int STRIDE = 1 << (8 - LOG);
  #pragma unroll
  for (int u = 0; u < 4; ++u) {
    const int bf = u * 64 + lane;                  // butterfly id 0..255
    const int j  = bf & (M4 - 1);
    const int i0 = ((bf >> LOG) << (LOG + 2)) | j;
    const int i1 = i0 + M4, i2 = i0 + 2 * M4, i3 = i0 + 3 * M4;
    const int p0 = SW(i0), p1 = SW(i1), p2 = SW(i2), p3 = SW(i3);
    float2 a = z[p0], b = z[p1], c = z[p2], d = z[p3];
    if (LOG > 0) {
      b = cmul(b, tw[j * STRIDE]);
      c = cmul(c, tw[2 * j * STRIDE]);
      d = cmul(d, tw[3 * j * STRIDE]);
    }
    const float2 t0 = make_float2(a.x + c.x, a.y + c.y);
    const float2 t1 = make_float2(a.x - c.x, a.y - c.y);
    const float2 t2 = make_float2(b.x + d.x, b.y + d.y);
    const float2 t3 = make_float2(b.x - d.x, b.y - d.y);
    z[p0] = make_float2(t0.x + t2.x, t0.y + t2.y);
    z[p1] = make_float2(t1.x + t3.y, t1.y - t3.x);   // t1 - i*t3
    z[p2] = make_float2(t0.x - t2.x, t0.y - t2.y);
    z[p3] = make_float2(t1.x - t3.y, t1.y + t3.x);   // t1 + i*t3
  }
}

// -------- stage 2: windowed rFFT magnitude, 1 wave = 1 frame --------
__global__ __launch_bounds__(256)
void stft_fft(const short* __restrict__ XP, const float* __restrict__ hann,
              const float2* __restrict__ Tst, const float2* __restrict__ Tun,
              float* __restrict__ out)
{
  __shared__ float2 zsh[4][1024];    // per-wave z, XOR-swizzled, no pad
  __shared__ float2 tst[1024];
  __shared__ float2 tun[1024];
  __shared__ float  mag[4][1025];    // staged magnitudes (4 consecutive frames)

  const int tid = threadIdx.x, wv = tid >> 6, lane = tid & 63;
  #pragma unroll
  for (int u = 0; u < 4; ++u) {
    tst[u * 256 + tid] = Tst[u * 256 + tid];
    tun[u * 256 + tid] = Tun[u * 256 + tid];
  }
  __syncthreads();

  float2* z = zsh[wv];
  const int bid = blockIdx.x;

  for (int q = 0; q < 4; ++q) {
    const int f = bid * 16 + q * 4 + wv;           // 4 consecutive frames per q
    const int b = f / TFR, t = f - b * TFR;
    const short* base = XP + (size_t)b * LPAD + (size_t)t * HOP;

    // load pair (x[2i], x[2i+1]), window, store digit-reversed (own z: no bar)
    #pragma unroll
    for (int u = 0; u < 16; ++u) {
      const int i = u * 64 + lane;
      const uint32_t pr = *(const uint32_t*)(base + 2 * i);
      const float xe = __builtin_bit_cast(float, pr << 16);
      const float xo = __builtin_bit_cast(float, pr & 0xffff0000u);
      const float2 h = *(const float2*)(hann + 2 * i);
      int r = __brev((unsigned)i) >> 22;               // 10-bit bit-reverse
      r = ((r & 0x155) << 1) | ((r >> 1) & 0x155);     // -> base-4 digit-reverse
      z[SW(r)] = make_float2(xe * h.x, xo * h.y);
    }

    fft_stage<0>(z, tst, lane);
    fft_stage<2>(z, tst, lane);
    fft_stage<4>(z, tst, lane);
    fft_stage<6>(z, tst, lane);
    fft_stage<8>(z, tst, lane);

    // unpack real FFT + magnitude -> mag[wv][*]
    #pragma unroll
    for (int v = 0; v < 16; ++v) {
      const int k = v * 64 + lane;
      const float2 Zk = z[SW(k)];
      const int km = (N2 - k) & (N2 - 1);
      const float2 Zm = z[SW(km)];
      const float xer = 0.5f * (Zk.x + Zm.x);
      const float xei = 0.5f * (Zk.y - Zm.y);
      const float xor_ = 0.5f * (Zk.y + Zm.y);
      const float xoi = -0.5f * (Zk.x - Zm.x);
      const float2 w = tun[k];
      const float Xr = xer + w.x * xor_ - w.y * xoi;
      const float Xi = xei + w.x * xoi + w.y * xor_;
      mag[wv][k] = sqrtf(Xr * Xr + Xi * Xi);
    }
    if (lane == 0) {                                   // Nyquist bin
      const float2 Z0 = z[0];
      mag[wv][N2] = fabsf(Z0.x - Z0.y);
    }
    __syncthreads();

    // write phase: per bin, 4 consecutive t -> 2x float2 (16B/line-touch)
    const int fq0 = bid * 16 + q * 4;
    const int b0 = fq0 / TFR, t0 = fq0 - b0 * TFR;
    if (t0 + 3 < TFR) {
      for (int kk = tid; kk < 1025; kk += 256) {
        float* p = out + (size_t)b0 * (CUT * TFR) + (size_t)kk * TFR + t0;
        *(float2*)p       = make_float2(mag[0][kk], mag[1][kk]);
        *(float2*)(p + 2) = make_float2(mag[2][kk], mag[3][kk]);
      }
    } else {                                           // batch-straddling group
      for (int kk = tid; kk < 1025; kk += 256) {
        #pragma unroll
        for (int w = 0; w < 4; ++w) {
          const int ff = fq0 + w;
          const int bb = ff / TFR, tt = ff - bb * TFR;
          out[(size_t)bb * (CUT * TFR) + (size_t)kk * TFR + tt] = mag[w][kk];
        }
      }
    }
    __syncthreads();
  }
}

// -------- fallback: reg-staged 128x128 MFMA GEMM (no ws needed) --------
typedef __attribute__((ext_vector_type(4))) float f32x4;

__global__ __launch_bounds__(256, 2)
void stft_gemm_fb(const float* __restrict__ basis, const float* __restrict__ x,
                  float* __restrict__ out)
{
  __shared__ alignas(16) short sA[2][128][64];
  __shared__ alignas(16) short sB[128][64];

  const int tid  = threadIdx.x;
  const int wave = tid >> 6;
  const int lane = tid & 63;
  const int n0 = blockIdx.x * 128;
  const int m0 = blockIdx.y * 128;

  f32x4 acc_r[4][4], acc_i[4][4];
  #pragma unroll
  for (int i = 0; i < 4; ++i)
    #pragma unroll
    for (int j = 0; j < 4; ++j) { acc_r[i][j] = (f32x4)0.f; acc_i[i][j] = (f32x4)0.f; }

  const int sr = tid >> 1;
  const int sh = (tid & 1) * 32;

  for (int k0 = 0; k0 < FILT; k0 += 64) {
    #pragma unroll
    for (int p = 0; p < 2; ++p) {
      const int k = m0 + sr;
      short8 v[4];
      if (k < CUT) {
        const float* src = basis + (size_t)(p * CUT + k) * FILT + k0 + sh;
        #pragma unroll
        for (int qq = 0; qq < 4; ++qq) {
          float4 a = *(const float4*)(src + qq * 8);
          float4 b = *(const float4*)(src + qq * 8 + 4);
          v[qq] = pack8(a, b);
        }
      } else {
        #pragma unroll
        for (int qq = 0; qq < 4; ++qq) v[qq] = (short8)(short)0;
      }
      #pragma unroll
      for (int qq = 0; qq < 4; ++qq) *(short8*)&sA[p][sr][sh + qq * 8] = v[qq];
    }
    {
      const int f = n0 + sr;
      short8 v[4];
      if (f < NFR) {
        const int b = f / TFR, t = f - b * TFR;
        const float* xb = x + (size_t)b * LSIG;
        const int j0 = t * HOP + k0 + sh - 1024;
        if (j0 >= 0 && j0 + 32 <= LSIG) {
          #pragma unroll
          for (int qq = 0; qq < 4; ++qq) {
            float4 a  = *(const float4*)(xb + j0 + qq * 8);
            float4 b2 = *(const float4*)(xb + j0 + qq * 8 + 4);
            v[qq] = pack8(a, b2);
          }
        } else {
          #pragma unroll
          for (int qq = 0; qq < 4; ++qq)
            #pragma unroll
            for (int e = 0; e < 8; ++e) {
              int j = j0 + qq * 8 + e;
              j = j < 0 ? -j : (j >= LSIG ? 2 * LSIG - 2 - j : j);
              v[qq][e] = bf16r(xb[j]);
            }
        }
      } else {
        #pragma unroll
        for (int qq = 0; qq < 4; ++qq) v[qq] = (short8)(short)0;
      }
      #pragma unroll
      for (int qq = 0; qq < 4; ++qq) *(short8*)&sB[sr][sh + qq * 8] = v[qq];
    }
    __syncthreads();

    const int ra = lane & 15;
    #pragma unroll
    for (int kk = 0; kk < 64; kk += 32) {
      const int col = kk + (lane >> 4) * 8;
      short8 arr[4], aii[4], bfr[4];
      #pragma unroll
      for (int i = 0; i < 4; ++i) {
        const int rm = (wave >> 1) * 64 + i * 16 + ra;
        arr[i] = *(const short8*)&sA[0][rm][col];
        aii[i] = *(const short8*)&sA[1][rm][col];
        const int rn = (wave & 1) * 64 + i * 16 + ra;
        bfr[i] = *(const short8*)&sB[rn][col];
      }
      #pragma unroll
      for (int i = 0; i < 4; ++i)
        #pragma unroll
        for (int j = 0; j < 4; ++j) {
          acc_r[i][j] = __builtin_amdgcn_mfma_f32_16x16x32_bf16(arr[i], bfr[j], acc_r[i][j], 0, 0, 0);
          acc_i[i][j] = __builtin_amdgcn_mfma_f32_16x16x32_bf16(aii[i], bfr[j], acc_i[i][j], 0, 0, 0);
        }
    }
    __syncthreads();
  }

  const int wm0 = m0 + (wave >> 1) * 64;
  const int wn0 = n0 + (wave & 1) * 64;
  const int cl = lane & 15;
  const int rg = (lane >> 4) * 4;
  #pragma unroll
  for (int j = 0; j < 4; ++j) {
    const int f = wn0 + j * 16 + cl;
    if (f >= NFR) continue;
    const int b = f / TFR, t = f - b * TFR;
    float* ob = out + (size_t)b * (CUT * TFR) + t;
    #pragma unroll
    for (int i = 0; i < 4; ++i) {
      #pragma unroll
      for (int r = 0; r < 4; ++r) {
        const int k = wm0 + i * 16 + rg + r;
        if (k < CUT) {
          float re = acc_r[i][j][r], im = acc_i[i][j][r];
          ob[(size_t)k * TFR] = sqrtf(re * re + im * im);
        }
      }
    }
  }
}

extern "C" void kernel_launch(void* const* d_in, const int* in_sizes, int n_in,
                              void* d_out, int out_size, void* d_ws, size_t ws_size,
                              hipStream_t stream) {
  const float* x     = (const float*)d_in[0];
  const float* basis = (const float*)d_in[1];
  float* out = (float*)d_out;

  const size_t sbytes = (size_t)NBATCH * LPAD * sizeof(short);   // 20,611,072
  const size_t hbytes = 2048 * sizeof(float);                    // 8 KB
  const size_t tbytes = 1024 * sizeof(float2);                   // 8 KB each

  if (ws_size >= sbytes + hbytes + 2 * tbytes) {
    short*  XP   = (short*)d_ws;
    float*  hann = (float*)((char*)d_ws + sbytes);
    float2* Tst  = (float2*)((char*)d_ws + sbytes + hbytes);
    float2* Tun  = (float2*)((char*)d_ws + sbytes + hbytes + tbytes);
    pad_signal<<<dim3((LPAD + 2047) / 2048, NBATCH), 256, 0, stream>>>(x, XP);
    make_tables<<<8, 256, 0, stream>>>(hann, Tst, Tun);
    stft_fft<<<NFR / 16, 256, 0, stream>>>(XP, hann, Tst, Tun, out);
  } else {
    stft_gemm_fb<<<dim3(157, 9), 256, 0, stream>>>(basis, x, out);
  }
}